// Round 3
// baseline (74.999 us; speedup 1.0000x reference)
//
#include <hip/hip_runtime.h>
#include <stdint.h>

// QuadraticConv2DTranspose via per-parity-class bf16 MFMA GEMM.
// Bed-of-nails stride-2 upsample => per output-parity class only 2/5/5/14 of
// the 55 features are live (+ pixel-independent bias vector).
//   out[m,n] = bias[n] + sum_k F[m,k] * W[k,n],  k = f*64 + c
// Round 3: W is pre-transposed/converted ONCE to bf16 fragment layout
// wt[l][n][c] by a prologue kernel. Main kernel: single barrier (x-tile
// stage), A-frags built in registers, B-frags loaded straight from L1/L2
// with data-independent addresses -> fully pipelined; no per-feature
// produce/consume chain (round 2 had 2*NF barriers/block, ~28 for OO).

typedef __attribute__((ext_vector_type(8))) short short8;
typedef __attribute__((ext_vector_type(4))) short short4v;
typedef __attribute__((ext_vector_type(4))) float floatx4;

__device__ __forceinline__ short f2bf(float f) {  // RTN-even fp32->bf16
  union { float f; uint32_t u; } v{f};
  uint32_t u = v.u;
  u += 0x7fffu + ((u >> 16) & 1u);
  return (short)(u >> 16);
}

// Per-class tables. Patch value j = x[hi+DY[j], wi+DX[j]].
// Feature f: kernel row L[f], value v[A[f]]*v[Bb[f]]; Bb[f]==NV -> linear.
template <int CLS> struct CI;
template <> struct CI<0> {  // ho even, wo even
  static constexpr int NV = 1, NF = 2;
  static constexpr int L[NF] = {30, 49};
  static constexpr int A[NF] = {0, 0};
  static constexpr int Bb[NF] = {0, 1};
  static constexpr int DY[NV] = {0};
  static constexpr int DX[NV] = {0};
};
template <> struct CI<1> {  // ho even, wo odd
  static constexpr int NV = 2, NF = 5;
  static constexpr int L[NF] = {24, 26, 35, 48, 50};
  static constexpr int A[NF] = {0, 0, 1, 0, 1};
  static constexpr int Bb[NF] = {0, 1, 1, 2, 2};
  static constexpr int DY[NV] = {0, 0};
  static constexpr int DX[NV] = {0, 1};
};
template <> struct CI<2> {  // ho odd, wo even
  static constexpr int NV = 2, NF = 5;
  static constexpr int L[NF] = {9, 15, 42, 46, 52};
  static constexpr int A[NF] = {0, 0, 1, 0, 1};
  static constexpr int Bb[NF] = {0, 1, 1, 2, 2};
  static constexpr int DY[NV] = {0, 1};
  static constexpr int DX[NV] = {0, 0};
};
template <> struct CI<3> {  // ho odd, wo odd
  static constexpr int NV = 4, NF = 14;
  static constexpr int L[NF] = {0, 2, 6, 8, 17, 21, 23, 39, 41, 44, 45, 47, 51, 53};
  static constexpr int A[NF] = {0, 0, 0, 0, 1, 1, 1, 2, 2, 3, 0, 1, 2, 3};
  static constexpr int Bb[NF] = {0, 1, 2, 3, 1, 2, 3, 2, 3, 3, 4, 4, 4, 4};
  static constexpr int DY[NV] = {0, 0, 1, 1};
  static constexpr int DX[NV] = {0, 1, 0, 1};
};

// Prologue: wt[(l*64+n)*64+c] = bf16(kern[(l*64+c)*64+n]); block 54 also
// reduces bias[n] = sum_c kern[54][c][n]. 55 blocks, ~1 us.
__global__ __launch_bounds__(256) void prep_w(const float* __restrict__ kern,
                                              short* __restrict__ wt,
                                              float* __restrict__ bias) {
  __shared__ float s[64][65];
  const int l = blockIdx.x;
  const int tid = threadIdx.x;
  for (int i = tid; i < 4096; i += 256)
    s[i >> 6][i & 63] = kern[(l << 12) + i];
  __syncthreads();
  if (l == 54 && tid < 64) {
    float a = 0.f;
    for (int c = 0; c < 64; ++c) a += s[c][tid];
    bias[tid] = a;
  }
  for (int i = tid; i < 1024; i += 256) {
    const int n = i >> 4, c4 = (i & 15) * 4;
    short4v v;
    v[0] = f2bf(s[c4 + 0][n]);
    v[1] = f2bf(s[c4 + 1][n]);
    v[2] = f2bf(s[c4 + 2][n]);
    v[3] = f2bf(s[c4 + 3][n]);
    *(short4v*)&wt[((l << 6) + n) * 64 + c4] = v;
  }
}

template <int CLS>
__device__ __forceinline__ void body(const float* __restrict__ x,
                                     const short* __restrict__ wt,
                                     const float* __restrict__ bias,
                                     float* __restrict__ out, int b, int hi0,
                                     int wi0, float (&sX)[45][68]) {
  using I = CI<CLS>;
  constexpr int NV = I::NV, NF = I::NF;
  const int tid = threadIdx.x;
  const int wave = tid >> 6, lane = tid & 63;
  const int quad = lane >> 4, l16 = lane & 15;
  const int mb = (wave & 1) * 16;   // wave's m-block (pixels)
  const int nh = (wave >> 1) * 32;  // wave's n-half (couts)
  const int m = mb + l16;           // A row (m = lane&15)
  const int ph = m >> 3, pw = m & 7;
  const int c8 = quad * 8;          // k-offset within 32-chunk (quad*8+j)

  // Stage the full x tile once: 5x9 positions x 64 ch fp32, zero OOB
  // (transpose-conv boundary handling falls out for free). Row stride 68
  // floats -> b128 reads alias 2-way only (free).
  for (int i = tid; i < 720; i += 256) {
    const int pos = i >> 4, c4 = (i & 15) * 4;
    const int hr = hi0 + pos / 9, wc = wi0 + pos % 9;
    float4 v = make_float4(0.f, 0.f, 0.f, 0.f);
    if (hr < 32 && wc < 32)
      v = *(const float4*)&x[(((b * 32) + hr) * 32 + wc) * 64 + c4];
    *(float4*)&sX[pos][c4] = v;
  }

  floatx4 acc[2];
#pragma unroll
  for (int nt = 0; nt < 2; ++nt) {  // C/D col = lane&15 -> same bias all rows
    const float bv = bias[nh + nt * 16 + l16];
    acc[nt] = floatx4{bv, bv, bv, bv};
  }

  __syncthreads();  // the only barrier in the kernel

  // Cache this lane's patch planes: 16 channels (8 per k-half) x NV values.
  float vpl[NV][16];
#pragma unroll
  for (int j = 0; j < NV; ++j) {
    const int pa = (ph + I::DY[j]) * 9 + (pw + I::DX[j]);
    *(float4*)&vpl[j][0] = *(const float4*)&sX[pa][c8];
    *(float4*)&vpl[j][4] = *(const float4*)&sX[pa][c8 + 4];
    *(float4*)&vpl[j][8] = *(const float4*)&sX[pa][32 + c8];
    *(float4*)&vpl[j][12] = *(const float4*)&sX[pa][32 + c8 + 4];
  }

#pragma unroll
  for (int chalf = 0; chalf < 2; ++chalf) {
#pragma unroll
    for (int f = 0; f < NF; ++f) {
      // B-frags: data-independent addresses -> compiler pipelines freely.
      const short* wr = wt + (I::L[f] * 64) * 64 + chalf * 32 + c8;
      const short8 b0 = *(const short8*)&wr[(nh + l16) * 64];
      const short8 b1 = *(const short8*)&wr[(nh + 16 + l16) * 64];
      short8 af;
#pragma unroll
      for (int j = 0; j < 8; ++j) {
        const float va = vpl[I::A[f]][chalf * 8 + j];
        const float v = (I::Bb[f] == NV) ? va : va * vpl[I::Bb[f]][chalf * 8 + j];
        af[j] = f2bf(v);
      }
      acc[0] = __builtin_amdgcn_mfma_f32_16x16x32_bf16(af, b0, acc[0], 0, 0, 0);
      acc[1] = __builtin_amdgcn_mfma_f32_16x16x32_bf16(af, b1, acc[1], 0, 0, 0);
    }
  }

  // Epilogue. D: col = n (lane&15 group), row = quad*4 + reg.
  constexpr int rh = CLS >> 1, rw = CLS & 1;
#pragma unroll
  for (int nt = 0; nt < 2; ++nt) {
    const int n = nh + nt * 16 + l16;
#pragma unroll
    for (int r = 0; r < 4; ++r) {
      const int mm = mb + quad * 4 + r;
      const int hi = hi0 + (mm >> 3), wi = wi0 + (mm & 7);
      const int ho = 2 * hi + rh, wo = 2 * wi + rw;
      out[(((b * 64) + ho) * 64 + wo) * 64 + n] = acc[nt][r];
    }
  }
}

__global__ __launch_bounds__(256, 4) void qct_main(const float* __restrict__ x,
                                                   const short* __restrict__ wt,
                                                   const float* __restrict__ bias,
                                                   float* __restrict__ out) {
  __shared__ float sX[45][68];  // 12.2 KB
  const int bid = blockIdx.x;
  // OO first: longest-job-first across CUs (7:1 per-class work ratio).
  int cls, blk;
  if (bid < 256)      { cls = 3; blk = bid; }
  else if (bid < 512) { cls = 1; blk = bid - 256; }
  else if (bid < 768) { cls = 2; blk = bid - 512; }
  else                { cls = 0; blk = bid - 768; }
  const int b = blk >> 5, tile = blk & 31;
  const int hi0 = (tile >> 2) * 4;  // 4x8 class-space tile = 32 pixels
  const int wi0 = (tile & 3) * 8;
  switch (cls) {
    case 0: body<0>(x, wt, bias, out, b, hi0, wi0, sX); break;
    case 1: body<1>(x, wt, bias, out, b, hi0, wi0, sX); break;
    case 2: body<2>(x, wt, bias, out, b, hi0, wi0, sX); break;
    case 3: body<3>(x, wt, bias, out, b, hi0, wi0, sX); break;
  }
}

extern "C" void kernel_launch(void* const* d_in, const int* in_sizes, int n_in,
                              void* d_out, int out_size, void* d_ws,
                              size_t ws_size, hipStream_t stream) {
  const float* x = (const float*)d_in[0];     // [8,32,32,64] f32
  const float* kern = (const float*)d_in[1];  // [55,64,64]   f32
  float* out = (float*)d_out;                 // [8,64,64,64] f32
  short* wt = (short*)d_ws;                   // 55*64*64 bf16 = 450,560 B
  float* bias = (float*)((char*)d_ws + 55 * 64 * 64 * 2);  // 64 floats

  prep_w<<<55, 256, 0, stream>>>(kern, wt, bias);
  qct_main<<<1024, 256, 0, stream>>>(x, wt, bias, out);
}